// Round 1
// 133.717 us; speedup vs baseline: 1.1362x; 1.1362x over previous
//
#include <hip/hip_runtime.h>

// Problem constants
#define IN_C   64
#define OUT_D  47          // (24-1)*2 - 2*1 + 3
#define XD     24
#define XSP    (XD*XD*XD)  // 13824
#define OSP    (OUT_D*OUT_D*OUT_D) // 103823
#define BATCH  16

// LDS: per-wave halo buffer for an 8x8x8 m-tile: 100 rows (10 z x 10 y),
// row stride RS=12 floats, row r holds x[gz=Bd-1+r/10][gy=Bh-1+r%10][gx=Bw-1..Bw+10]
// at idx 0..11 (only 0..9 ever read).
#define RS     12
#define NR     100
#define WBUF   (NR*RS)     // 1200 floats per wave

typedef float f4u  __attribute__((ext_vector_type(4), aligned(4)));
typedef float f4a8 __attribute__((ext_vector_type(4), aligned(8)));

// Effective weights: weff[c*64 + (pd*2+dd)*16 + (((ph*2+pw)*2+dh)*2+dw)]
__global__ void weff_prep(const float* __restrict__ w, float* __restrict__ weff) {
    int c = threadIdx.x;   // 64 threads
    float wv[27];
    const float* wc = w + (size_t)c * 64 * 27;   // weight[c][0][*]
    #pragma unroll
    for (int z = 0; z < 27; z++) wv[z] = wc[z];
    const int msk[2][2] = {{4, 3}, {6, 1}};
    #pragma unroll
    for (int pd = 0; pd < 2; pd++)
    #pragma unroll
    for (int dd = 0; dd < 2; dd++)
    #pragma unroll
    for (int ph = 0; ph < 2; ph++)
    #pragma unroll
    for (int pw = 0; pw < 2; pw++)
    #pragma unroll
    for (int dh = 0; dh < 2; dh++)
    #pragma unroll
    for (int dw = 0; dw < 2; dw++) {
        float s = 0.f;
        for (int zd = 0; zd < 3; zd++) if ((msk[pd][dd] >> zd) & 1)
            for (int zh = 0; zh < 3; zh++) if ((msk[ph][dh] >> zh) & 1)
                for (int zw = 0; zw < 3; zw++) if ((msk[pw][dw] >> zw) & 1)
                    s += wv[zd * 9 + zh * 3 + zw];
        weff[c * 64 + (pd * 2 + dd) * 16 + (((ph * 2 + pw) * 2 + dh) * 2 + dw)] = s;
    }
}

// 432 blocks = 27 sp-tiles (8x8x8 in m-space) x 16 n (n in low 4 bits).
// 256 threads = 4 waves; wave wv reduces channels [16wv,16wv+16) over the
// block's 8x8x8 m-tile in a wave-PRIVATE LDS buffer (no barriers in loop).
// Lane owns a 2x2x2 m-block: lz=L>>4 (z-pair), lyy=(L>>2)&3 (y-pair),
// lxx=L&3 (x-pair). 64 accs/thread -> each 16B LDS read feeds 2x the FMAs
// of the previous 1x1x4 layout (LDS instr count halves).
__global__ __launch_bounds__(256, 2) void tconv(const float* __restrict__ x,
                                                const float* __restrict__ weff,
                                                const float* __restrict__ bias,
                                                float* __restrict__ out) {
    __shared__ float xs[4864];      // 19 KB: 4x1200 staging, overlaid 2x2048 reduce
    int braw = blockIdx.x;
    // XCD-contiguous bijective swizzle (432 % 8 == 0): neighboring sp-tiles of
    // the same image land on the same XCD's L2.
    int b = (braw & 7) * 54 + (braw >> 3);
    const int sp = b >> 4;          // 0..26
    const int n  = b & 15;
    const int tz = sp / 9;
    const int r9 = sp - tz * 9;
    const int ty = r9 / 3;
    const int tx = r9 - ty * 3;
    const int Bd = tz * 8, Bh = ty * 8, Bw = tx * 8;

    const int tid = threadIdx.x;
    const int wv  = tid >> 6;
    const int L   = tid & 63;
    const int lz  = L >> 4;         // 0..3  (m-z pair)
    const int lyy = (L >> 2) & 3;   // 0..3  (m-y pair)
    const int lxx = L & 3;          // 0..3  (m-x pair)

    float* ws = xs + wv * WBUF;

    // one-time zero fill (invalid halo rows must read as 0)
    #pragma unroll
    for (int i = 0; i < 19; i++) xs[tid + 256 * i] = 0.f;
    __syncthreads();

    // ---- channel-invariant staging descriptors: 5 units/lane ----
    // unit e = k*64 + L (u = x-quad 0..2, r = row 0..99)
    int gofs[5], lad[5], et[5];     // et: -1 skip, 0 full, 1 shift-left, 2 scalar
    #pragma unroll
    for (int k = 0; k < 5; k++) {
        int e = k * 64 + L;
        int u = e / 100;
        int r = e - u * 100;
        int z = r / 10;
        int y = r - z * 10;
        int gz = Bd - 1 + z, gy = Bh - 1 + y;
        bool rv = (e < 300) && ((unsigned)gz < (unsigned)XD) &&
                  ((unsigned)gy < (unsigned)XD);
        int gxs = Bw - 1 + 4 * u;
        int t;
        if (!rv) t = -1;
        else if (gxs < 0) t = 1;          // Bw=0,u=0: gx -1..2
        else if (gxs + 3 > XD - 1) t = 2; // Bw=16,u=2: gx 23..26
        else t = 0;
        et[k] = t;
        gofs[k] = (gz * XD + gy) * XD + (gxs < 0 ? 0 : gxs);
        lad[k] = r * RS + 4 * u;
    }

    const float* xg = x + ((size_t)n * IN_C + wv * 16) * XSP;

    // ---- prologue prefetch: channel 0 ----
    float4 pre[5];
    #pragma unroll
    for (int k = 0; k < 5; k++) {
        if (et[k] < 0) pre[k] = make_float4(0.f, 0.f, 0.f, 0.f);
        else if (et[k] == 2) pre[k] = make_float4(xg[gofs[k]], 0.f, 0.f, 0.f);
        else { f4u q = *(const f4u*)(xg + gofs[k]);
               pre[k] = make_float4(q.x, q.y, q.z, q.w); }
    }

    float acc[2][2][2][2][2][2];    // [mzi][myi][mxi][pd][ph][pw]
    {
        float* af = &acc[0][0][0][0][0][0];
        #pragma unroll
        for (int i = 0; i < 64; i++) af[i] = 0.f;
    }

    // lane-fixed row base: rows (2lz+za)*10 + (2lyy+ya), x offset 2lxx
    const int rb = (lz * 20 + lyy * 2) * RS + 2 * lxx;

    // ---- barrier-free channel loop (wave-private buffer) ----
    #pragma unroll 1
    for (int cc = 0; cc < 16; cc++) {
        #pragma unroll
        for (int k = 0; k < 5; k++) {
            if (et[k] >= 0) {
                float4 c = pre[k];
                if (et[k] == 1) c = make_float4(0.f, c.x, c.y, c.z);
                *(float4*)&ws[lad[k]] = c;
            }
        }
        if (cc + 1 < 16) {
            const float* xc = xg + (size_t)(cc + 1) * XSP;
            #pragma unroll
            for (int k = 0; k < 5; k++) {
                if (et[k] < 0) continue;
                if (et[k] == 2) pre[k] = make_float4(xc[gofs[k]], 0.f, 0.f, 0.f);
                else { f4u q = *(const f4u*)(xc + gofs[k]);
                       pre[k] = make_float4(q.x, q.y, q.z, q.w); }
            }
        }

        const float* Wc = weff + (size_t)(wv * 16 + cc) * 64;  // wave-uniform
        #pragma unroll
        for (int za = 0; za < 4; za++) {
            float xv[4][4];
            #pragma unroll
            for (int ya = 0; ya < 4; ya++) {
                f4a8 v = *(const f4a8*)&ws[rb + (za * 10 + ya) * RS];
                xv[ya][0] = v.x; xv[ya][1] = v.y;
                xv[ya][2] = v.z; xv[ya][3] = v.w;
            }
            // za = mzi + pd + dd
            #pragma unroll
            for (int mzi = 0; mzi < 2; mzi++)
            #pragma unroll
            for (int pd = 0; pd < 2; pd++)
            #pragma unroll
            for (int dd = 0; dd < 2; dd++) {
                if (mzi + pd + dd != za) continue;
                const float* Wg = Wc + (pd * 2 + dd) * 16;
                #pragma unroll
                for (int ph = 0; ph < 2; ph++)
                #pragma unroll
                for (int pw = 0; pw < 2; pw++)
                #pragma unroll
                for (int dh = 0; dh < 2; dh++)
                #pragma unroll
                for (int dw = 0; dw < 2; dw++) {
                    const float wgt = Wg[((ph * 2 + pw) * 2 + dh) * 2 + dw];
                    #pragma unroll
                    for (int myi = 0; myi < 2; myi++)
                    #pragma unroll
                    for (int mxi = 0; mxi < 2; mxi++)
                        acc[mzi][myi][mxi][pd][ph][pw] +=
                            wgt * xv[myi + ph + dh][mxi + pw + dw];
                }
            }
        }
    }

    // ---- in-block tree reduction over the 4 channel-groups ----
    // payload = 64 floats/lane -> done in halves of 8 float4-groups (16 KB fits)
    __syncthreads();
    #pragma unroll
    for (int h = 0; h < 2; h++) {
        if (wv == 1 || wv == 3) {
            float* R = xs + (wv == 1 ? 0 : 2048);
            #pragma unroll
            for (int g8 = 0; g8 < 8; g8++) {
                const int g = h * 8 + g8;
                const int mzi = (g >> 3) & 1, myi = (g >> 2) & 1;
                const int mxi = (g >> 1) & 1, pd = g & 1;
                *(float4*)&R[(g8 * 64 + L) * 4] = make_float4(
                    acc[mzi][myi][mxi][pd][0][0], acc[mzi][myi][mxi][pd][0][1],
                    acc[mzi][myi][mxi][pd][1][0], acc[mzi][myi][mxi][pd][1][1]);
            }
        }
        __syncthreads();
        if (wv == 0 || wv == 2) {
            const float* R = xs + (wv == 0 ? 0 : 2048);
            #pragma unroll
            for (int g8 = 0; g8 < 8; g8++) {
                const int g = h * 8 + g8;
                const int mzi = (g >> 3) & 1, myi = (g >> 2) & 1;
                const int mxi = (g >> 1) & 1, pd = g & 1;
                float4 v = *(const float4*)&R[(g8 * 64 + L) * 4];
                acc[mzi][myi][mxi][pd][0][0] += v.x;
                acc[mzi][myi][mxi][pd][0][1] += v.y;
                acc[mzi][myi][mxi][pd][1][0] += v.z;
                acc[mzi][myi][mxi][pd][1][1] += v.w;
            }
        }
        __syncthreads();
    }
    #pragma unroll
    for (int h = 0; h < 2; h++) {
        if (wv == 2) {
            #pragma unroll
            for (int g8 = 0; g8 < 8; g8++) {
                const int g = h * 8 + g8;
                const int mzi = (g >> 3) & 1, myi = (g >> 2) & 1;
                const int mxi = (g >> 1) & 1, pd = g & 1;
                *(float4*)&xs[(g8 * 64 + L) * 4] = make_float4(
                    acc[mzi][myi][mxi][pd][0][0], acc[mzi][myi][mxi][pd][0][1],
                    acc[mzi][myi][mxi][pd][1][0], acc[mzi][myi][mxi][pd][1][1]);
            }
        }
        __syncthreads();
        if (wv == 0) {
            #pragma unroll
            for (int g8 = 0; g8 < 8; g8++) {
                const int g = h * 8 + g8;
                const int mzi = (g >> 3) & 1, myi = (g >> 2) & 1;
                const int mxi = (g >> 1) & 1, pd = g & 1;
                float4 v = *(const float4*)&xs[(g8 * 64 + L) * 4];
                acc[mzi][myi][mxi][pd][0][0] += v.x;
                acc[mzi][myi][mxi][pd][0][1] += v.y;
                acc[mzi][myi][mxi][pd][1][0] += v.z;
                acc[mzi][myi][mxi][pd][1][1] += v.w;
            }
        }
        __syncthreads();
    }

    // ---- epilogue: plain stores by wave 0 ----
    if (wv == 0) {
        const float b0 = bias[0] * 64.0f;
        float* on = out + (size_t)n * OSP;
        #pragma unroll
        for (int mzi = 0; mzi < 2; mzi++)
        #pragma unroll
        for (int pd = 0; pd < 2; pd++) {
            const int od = 2 * (Bd + 2 * lz + mzi) + pd;
            if (od >= OUT_D) continue;
            #pragma unroll
            for (int myi = 0; myi < 2; myi++)
            #pragma unroll
            for (int ph = 0; ph < 2; ph++) {
                const int oh = 2 * (Bh + 2 * lyy + myi) + ph;
                if (oh >= OUT_D) continue;
                const size_t rowo = ((size_t)od * OUT_D + oh) * OUT_D;
                #pragma unroll
                for (int mxi = 0; mxi < 2; mxi++)
                #pragma unroll
                for (int pw = 0; pw < 2; pw++) {
                    const int ow = 2 * (Bw + 2 * lxx + mxi) + pw;
                    if (ow < OUT_D)
                        on[rowo + ow] =
                            acc[mzi][myi][mxi][pd][0 + (ph)][0 + (pw)] * 0.f +
                            acc[mzi][myi][mxi][pd][ph][pw] * 64.0f + b0;
                }
            }
        }
    }
}

extern "C" void kernel_launch(void* const* d_in, const int* in_sizes, int n_in,
                              void* d_out, int out_size, void* d_ws, size_t ws_size,
                              hipStream_t stream) {
    const float* x      = (const float*)d_in[0];
    const float* weight = (const float*)d_in[1];
    const float* bias   = (const float*)d_in[2];
    float* out = (float*)d_out;
    float* weff = (float*)d_ws;        // 64*64 floats = 16 KB

    hipLaunchKernelGGL(weff_prep, dim3(1), dim3(64), 0, stream, weight, weff);

    dim3 grid(27 * BATCH, 1, 1);       // 432 blocks, n in low 4 bits
    hipLaunchKernelGGL(tconv, grid, dim3(256), 0, stream, x, weff, bias, out);
}